// Round 1
// baseline (1517.035 us; speedup 1.0000x reference)
//
#include <hip/hip_runtime.h>

#define TSEQ 512
#define IND 64
#define HID 10
#define NG 40   // 4*HID gates

__device__ __forceinline__ float lane_f(float v, int l) {
  return __builtin_bit_cast(float, __builtin_amdgcn_readlane(__builtin_bit_cast(int, v), l));
}

__global__ __launch_bounds__(64, 4) void lstm_fused(
    const float* __restrict__ x, const float* __restrict__ W_ih,
    const float* __restrict__ W_hh, const float* __restrict__ b_ih,
    const float* __restrict__ b_hh, float* __restrict__ out_seq,
    float* __restrict__ out_h)
{
  const int b    = blockIdx.x;
  const int lane = threadIdx.x;           // 0..63; lanes 0..39 own gates
  const int g    = lane < NG ? lane : NG - 1;
  const int tt   = g / HID;               // 0=i, 1=f, 2=g(tanh), 3=o

  // Per-gate weights live in registers for all 512 steps.
  float wih[IND];
#pragma unroll
  for (int k = 0; k < IND; ++k) wih[k] = W_ih[g * IND + k];
  float whh[HID];
#pragma unroll
  for (int u = 0; u < HID; ++u) whh[u] = W_hh[g * HID + u];
  const float bias = b_ih[g] + b_hh[g];

  // sigmoid(y) = 1/(1+exp2(-log2e*y)); tanh(y) = 2*sigmoid(2y)-1.
  const float mscale = (tt == 2) ? -2.885390081777927f : -1.4426950408889634f;
  const float aMul   = (tt == 2) ? 2.0f : 1.0f;
  const float aAdd   = (tt == 2) ? -1.0f : 0.0f;

  float h = 0.0f, c = 0.0f;               // valid on lanes 0..9 (unit = lane)
  const float* xrow = x + (size_t)b * TSEQ * IND;   // wave-uniform pointer
  float* orow = out_seq + (size_t)b * TSEQ * HID;

  for (int t = 0; t < TSEQ; ++t) {
    float acc = bias;
    // Hidden projection: broadcast h[u] from lane u via readlane (SGPR operand).
#pragma unroll
    for (int u = 0; u < HID; ++u)
      acc = fmaf(lane_f(h, u), whh[u], acc);
    // Input projection: xrow[k] is wave-uniform -> scalar loads + v_fmac(s,v).
#pragma unroll
    for (int k = 0; k < IND; ++k)
      acc = fmaf(xrow[k], wih[k], acc);

    // Gate activation (sigmoid for i,f,o; tanh for g) in a uniform path.
    float e   = __builtin_amdgcn_exp2f(mscale * acc);
    float s   = __builtin_amdgcn_rcpf(1.0f + e);
    float act = fmaf(aMul, s, aAdd);

    // Gather i,f,g,o for unit = lane (meaningful on lanes 0..9).
    float iv = __shfl(act, lane);
    float fv = __shfl(act, lane + 10);
    float gv = __shfl(act, lane + 20);
    float ov = __shfl(act, lane + 30);

    c = fmaf(fv, c, iv * gv);
    float e2 = __builtin_amdgcn_exp2f(-2.885390081777927f * c);
    float th = fmaf(2.0f, __builtin_amdgcn_rcpf(1.0f + e2), -1.0f);
    h = ov * th;

    if (lane < HID) orow[t * HID + lane] = h;
    xrow += IND;
  }
  if (lane < HID) out_h[(size_t)b * HID + lane] = h;
}

extern "C" void kernel_launch(void* const* d_in, const int* in_sizes, int n_in,
                              void* d_out, int out_size, void* d_ws, size_t ws_size,
                              hipStream_t stream) {
  const float* x    = (const float*)d_in[0];
  const float* W_ih = (const float*)d_in[1];
  const float* W_hh = (const float*)d_in[2];
  const float* b_ih = (const float*)d_in[3];
  const float* b_hh = (const float*)d_in[4];

  const int BATCH = 4096;
  float* out_seq = (float*)d_out;                          // [B, T, H]
  float* out_h   = (float*)d_out + (size_t)BATCH * TSEQ * HID;  // [B, H]

  lstm_fused<<<dim3(BATCH), dim3(64), 0, stream>>>(
      x, W_ih, W_hh, b_ih, b_hh, out_seq, out_h);
}

// Round 2
// 1227.263 us; speedup vs baseline: 1.2361x; 1.2361x over previous
//
#include <hip/hip_runtime.h>

#define TSEQ 512
#define IND 64
#define HID 10
#define NG 40
#define BATCH 4096
#define ROWS (BATCH * TSEQ)          // 2,097,152 rows of x

__device__ __forceinline__ float lane_f(float v, int l) {
  return __builtin_bit_cast(float, __builtin_amdgcn_readlane(__builtin_bit_cast(int, v), l));
}

// Phase 1: xg[row][g] = sum_k x[row][k] * W_ih[g][k] + b_ih[g] + b_hh[g]
// One thread per row. x row in 64 VGPRs; weights are wave-uniform -> SGPRs.
__global__ __launch_bounds__(256) void input_proj(
    const float* __restrict__ x, const float* __restrict__ W_ih,
    const float* __restrict__ b_ih, const float* __restrict__ b_hh,
    float* __restrict__ xg)
{
  const long long row = (long long)blockIdx.x * 256 + threadIdx.x;
  const float4* xv = (const float4*)(x + row * IND);
  float xr[IND];
#pragma unroll
  for (int i = 0; i < 16; ++i) {
    float4 v = xv[i];
    xr[4*i+0] = v.x; xr[4*i+1] = v.y; xr[4*i+2] = v.z; xr[4*i+3] = v.w;
  }
  float* og = xg + row * NG;
#pragma unroll 1
  for (int gc = 0; gc < 10; ++gc) {       // 4 gates per iteration
    const float* w = W_ih + gc * 4 * IND; // wave-uniform -> s_load
    float a0 = b_ih[gc*4+0] + b_hh[gc*4+0];
    float a1 = b_ih[gc*4+1] + b_hh[gc*4+1];
    float a2 = b_ih[gc*4+2] + b_hh[gc*4+2];
    float a3 = b_ih[gc*4+3] + b_hh[gc*4+3];
#pragma unroll
    for (int k = 0; k < IND; ++k) {
      a0 = fmaf(xr[k], w[k],         a0);
      a1 = fmaf(xr[k], w[IND + k],   a1);
      a2 = fmaf(xr[k], w[2*IND + k], a2);
      a3 = fmaf(xr[k], w[3*IND + k], a3);
    }
    float4 o; o.x = a0; o.y = a1; o.z = a2; o.w = a3;
    ((float4*)og)[gc] = o;                // row*160 B base: 16B-aligned
  }
}

// Phase 2: the serial recurrence. One wave per batch element; lane = gate.
__global__ __launch_bounds__(64) void lstm_rec(
    const float* __restrict__ xg, const float* __restrict__ W_hh,
    float* __restrict__ out_seq, float* __restrict__ out_h)
{
  const int b    = blockIdx.x;
  const int lane = threadIdx.x;
  const int g    = lane < NG ? lane : NG - 1;
  const int li   = lane < NG ? lane : 0;       // safe load index
  const int tt   = g / HID;                    // 0=i,1=f,2=g(tanh),3=o

  const float mscale = (tt == 2) ? -2.885390081777927f : -1.4426950408889634f;
  const float aMul   = (tt == 2) ? 2.0f : 1.0f;
  const float aAdd   = (tt == 2) ? -1.0f : 0.0f;

  // Pre-scaled hidden weights: gates_scaled = mscale*(xg + Whh·h)
  float whh[HID];
#pragma unroll
  for (int u = 0; u < HID; ++u) whh[u] = W_hh[g * HID + u] * mscale;

  const float* xr = xg + (size_t)b * TSEQ * NG;
  float* orow = out_seq + (size_t)b * TSEQ * HID;

  float h = 0.0f, c = 0.0f;
  float xv = xr[li];                           // prefetch t=0
  for (int t = 0; t < TSEQ; ++t) {
    float xnext = (t < TSEQ - 1) ? xr[(t + 1) * NG + li] : 0.0f;  // hidden under compute
    float acc = xv * mscale;
#pragma unroll
    for (int u = 0; u < HID; ++u)
      acc = fmaf(lane_f(h, u), whh[u], acc);

    float e   = __builtin_amdgcn_exp2f(acc);
    float s   = __builtin_amdgcn_rcpf(1.0f + e);
    float act = fmaf(aMul, s, aAdd);

    float iv = __shfl(act, lane);
    float fv = __shfl(act, lane + 10);
    float gv = __shfl(act, lane + 20);
    float ov = __shfl(act, lane + 30);

    c = fmaf(fv, c, iv * gv);
    float e2 = __builtin_amdgcn_exp2f(-2.885390081777927f * c);
    float th = fmaf(2.0f, __builtin_amdgcn_rcpf(1.0f + e2), -1.0f);
    h = ov * th;

    if (lane < HID) orow[t * HID + lane] = h;
    xv = xnext;
  }
  if (lane < HID) out_h[(size_t)b * HID + lane] = h;
}

extern "C" void kernel_launch(void* const* d_in, const int* in_sizes, int n_in,
                              void* d_out, int out_size, void* d_ws, size_t ws_size,
                              hipStream_t stream) {
  const float* x    = (const float*)d_in[0];
  const float* W_ih = (const float*)d_in[1];
  const float* W_hh = (const float*)d_in[2];
  const float* b_ih = (const float*)d_in[3];
  const float* b_hh = (const float*)d_in[4];

  float* xg      = (float*)d_ws;                                // [ROWS, 40] = 336 MB
  float* out_seq = (float*)d_out;                               // [B, T, H]
  float* out_h   = (float*)d_out + (size_t)BATCH * TSEQ * HID;  // [B, H]

  input_proj<<<dim3(ROWS / 256), dim3(256), 0, stream>>>(x, W_ih, b_ih, b_hh, xg);
  lstm_rec<<<dim3(BATCH), dim3(64), 0, stream>>>(xg, W_hh, out_seq, out_h);
}

// Round 3
// 1066.618 us; speedup vs baseline: 1.4223x; 1.1506x over previous
//
#include <hip/hip_runtime.h>
#include <hip/hip_fp16.h>

typedef float f32x2 __attribute__((ext_vector_type(2)));

#define TSEQ 512
#define IND 64
#define HID 10
#define NG 40
#define BATCH 4096
#define ROWS (BATCH * TSEQ)
#define RPB 256          // rows per block in phase 1
#define LSTRIDE 21       // padded LDS row stride in dwords (20 data + 1)

#define L2E   1.4426950408889634f
#define L2E2  2.8853900817779268f

__device__ __forceinline__ float lane_f(float v, int l) {
  return __builtin_bit_cast(float, __builtin_amdgcn_readlane(__builtin_bit_cast(int, v), l));
}

// Phase 1: xg[row][g] = fp16( (x[row]·W_ih[g] + b_ih[g] + b_hh[g]) * scale_g )
// scale_g = -log2e for i,f,o gates; -2*log2e for g gate (folds the exp2 args).
// Results staged in LDS, written out fully coalesced as dwordx4.
__global__ __launch_bounds__(256) void input_proj(
    const float* __restrict__ x, const float* __restrict__ W_ih,
    const float* __restrict__ b_ih, const float* __restrict__ b_hh,
    unsigned int* __restrict__ xg)           // packed half2, ROWS*20 dwords
{
  __shared__ unsigned int st[RPB * LSTRIDE];
  const int tid = threadIdx.x;
  const long long row = (long long)blockIdx.x * RPB + tid;

  // x row -> 32 packed f32x2 (64 VGPRs)
  f32x2 xr[32];
  const float4* xv = (const float4*)(x + row * IND);
#pragma unroll
  for (int i = 0; i < 16; ++i) {
    float4 v = xv[i];
    xr[2*i]   = f32x2{v.x, v.y};
    xr[2*i+1] = f32x2{v.z, v.w};
  }

#pragma unroll 1
  for (int gc = 0; gc < 10; ++gc) {          // 4 gates per iteration
    const f32x2* w0 = (const f32x2*)(W_ih + (4*gc + 0) * IND);  // wave-uniform
    const f32x2* w1 = (const f32x2*)(W_ih + (4*gc + 1) * IND);
    const f32x2* w2 = (const f32x2*)(W_ih + (4*gc + 2) * IND);
    const f32x2* w3 = (const f32x2*)(W_ih + (4*gc + 3) * IND);
    f32x2 a0 = {0.f, 0.f}, a1 = {0.f, 0.f}, a2 = {0.f, 0.f}, a3 = {0.f, 0.f};
#pragma unroll
    for (int k = 0; k < 32; ++k) {
      a0 = __builtin_elementwise_fma(xr[k], w0[k], a0);
      a1 = __builtin_elementwise_fma(xr[k], w1[k], a1);
      a2 = __builtin_elementwise_fma(xr[k], w2[k], a2);
      a3 = __builtin_elementwise_fma(xr[k], w3[k], a3);
    }
    float s0 = ((4*gc + 0) / 10 == 2) ? -L2E2 : -L2E;
    float s1 = ((4*gc + 1) / 10 == 2) ? -L2E2 : -L2E;
    float s2 = ((4*gc + 2) / 10 == 2) ? -L2E2 : -L2E;
    float s3 = ((4*gc + 3) / 10 == 2) ? -L2E2 : -L2E;
    float g0 = (a0.x + a0.y + b_ih[4*gc + 0] + b_hh[4*gc + 0]) * s0;
    float g1 = (a1.x + a1.y + b_ih[4*gc + 1] + b_hh[4*gc + 1]) * s1;
    float g2 = (a2.x + a2.y + b_ih[4*gc + 2] + b_hh[4*gc + 2]) * s2;
    float g3 = (a3.x + a3.y + b_ih[4*gc + 3] + b_hh[4*gc + 3]) * s3;
    _Float16 q0 = (_Float16)g0, q1 = (_Float16)g1, q2 = (_Float16)g2, q3 = (_Float16)g3;
    unsigned p01 = (unsigned)__builtin_bit_cast(unsigned short, q0) |
                   ((unsigned)__builtin_bit_cast(unsigned short, q1) << 16);
    unsigned p23 = (unsigned)__builtin_bit_cast(unsigned short, q2) |
                   ((unsigned)__builtin_bit_cast(unsigned short, q3) << 16);
    st[tid * LSTRIDE + 2*gc]     = p01;
    st[tid * LSTRIDE + 2*gc + 1] = p23;
  }
  __syncthreads();

  // Coalesced copy-out: 256 rows x 20 dwords = 5120 dwords per block.
  const long long obase = (long long)blockIdx.x * (RPB * 20);
#pragma unroll
  for (int it = 0; it < 5; ++it) {
    int d0 = it * 1024 + tid * 4;            // d0 % 4 == 0 -> never crosses a 20-dword row
    int r = d0 / 20, m = d0 % 20;
    const unsigned* p = &st[r * LSTRIDE + m];
    uint4 vv; vv.x = p[0]; vv.y = p[1]; vv.z = p[2]; vv.w = p[3];
    *(uint4*)(xg + obase + d0) = vv;
  }
}

// Phase 2: serial recurrence. One wave per batch element; lane = gate.
__global__ __launch_bounds__(64) void lstm_rec(
    const _Float16* __restrict__ xg, const float* __restrict__ W_hh,
    float* __restrict__ out_seq, float* __restrict__ out_h)
{
  __shared__ float hbuf[80];
  const int b    = blockIdx.x;
  const int lane = threadIdx.x;
  const int g    = lane < NG ? lane : NG - 1;
  const int li   = lane < NG ? lane : 0;
  const int tt   = g / HID;

  const float aMul = (tt == 2) ? 2.0f : 1.0f;
  const float aAdd = (tt == 2) ? -1.0f : 0.0f;
  const float mscale = (tt == 2) ? -L2E2 : -L2E;

  float whh[HID];
#pragma unroll
  for (int u = 0; u < HID; ++u) whh[u] = W_hh[g * HID + u] * mscale;

  const _Float16* xr = xg + (size_t)b * TSEQ * NG + li;
  float* orow = out_seq + (size_t)b * TSEQ * HID;

  float h = 0.0f, c = 0.0f;
  _Float16 xb[8];
#pragma unroll
  for (int j = 0; j < 8; ++j) xb[j] = xr[j * NG];      // 8-deep prefetch

  for (int t0 = 0; t0 < TSEQ; t0 += 8) {
#pragma unroll
    for (int j = 0; j < 8; ++j) {
      float acc = (float)xb[j];                        // pre-scaled by mscale
      if (t0 + 8 < TSEQ) xb[j] = xr[(t0 + j + 8) * NG];

#pragma unroll
      for (int u = 0; u < HID; ++u)
        acc = fmaf(lane_f(h, u), whh[u], acc);

      float e   = __builtin_amdgcn_exp2f(acc);
      float s   = __builtin_amdgcn_rcpf(1.0f + e);
      float act = fmaf(aMul, s, aAdd);                 // sigmoid (i,f,o) / tanh (g)

      float iv = __shfl(act, lane);
      float fv = __shfl(act, lane + 10);
      float gv = __shfl(act, lane + 20);
      float ov = __shfl(act, lane + 30);

      c = fmaf(fv, c, iv * gv);
      float e2 = __builtin_amdgcn_exp2f(-L2E2 * c);
      float th = fmaf(2.0f, __builtin_amdgcn_rcpf(1.0f + e2), -1.0f);
      h = ov * th;

      if (lane < HID) hbuf[j * HID + lane] = h;
    }
    __syncthreads();                                   // single wave: cheap fence
    if (lane < 40) {
      float2 p; p.x = hbuf[2 * lane]; p.y = hbuf[2 * lane + 1];
      ((float2*)(orow + t0 * HID))[lane] = p;          // 320 B contiguous store
    }
    __syncthreads();
  }
  if (lane < HID) out_h[(size_t)b * HID + lane] = h;
}

extern "C" void kernel_launch(void* const* d_in, const int* in_sizes, int n_in,
                              void* d_out, int out_size, void* d_ws, size_t ws_size,
                              hipStream_t stream) {
  const float* x    = (const float*)d_in[0];
  const float* W_ih = (const float*)d_in[1];
  const float* W_hh = (const float*)d_in[2];
  const float* b_ih = (const float*)d_in[3];
  const float* b_hh = (const float*)d_in[4];

  unsigned int* xg = (unsigned int*)d_ws;                       // ROWS*20 dwords (168 MB)
  float* out_seq = (float*)d_out;                               // [B, T, H]
  float* out_h   = (float*)d_out + (size_t)BATCH * TSEQ * HID;  // [B, H]

  input_proj<<<dim3(ROWS / RPB), dim3(RPB), 0, stream>>>(x, W_ih, b_ih, b_hh, xg);
  lstm_rec<<<dim3(BATCH), dim3(64), 0, stream>>>((const _Float16*)xg, W_hh, out_seq, out_h);
}